// Round 10
// baseline (43.899 us; speedup 1.0000x reference)
//
#include <hip/hip_runtime.h>

#define NB 128
#define NC 16
#define NT 16384
#define NW 4096
#define TPB 256
#define SPANROW 512          // LDS row capacity (floats); max true span ~455

typedef float f32x4 __attribute__((ext_vector_type(4)));

// One block = (sample b, 256 consecutive outputs), all 16 channels.
// XCD-swizzled 1D grid; t-strided lane mapping (t = t0 + tq + 64*i) so LDS
// gather lane-stride ~= warp slope (0.5..1.75 words) -> conflict-free.
__global__ __launch_bounds__(256) void rww_kernel(
    const float* __restrict__ x,
    const int* __restrict__ window_starts,
    const int* __restrict__ new_len,
    float* __restrict__ out)
{
    __shared__ float lds[NC][SPANROW];

    // decode XCD-swizzled block id: i = ((b>>3)*64 + tc)*8 + (b&7)
    const int i_  = blockIdx.x;
    const int xcd = i_ & 7;
    const int j_  = i_ >> 3;
    const int tc  = j_ & 63;
    const int b   = ((j_ >> 6) << 3) + xcd;

    const int t0  = tc * TPB;
    const int tid = threadIdx.x;

    const int s  = window_starts[b];
    const int nl = new_len[b];
    const float sf  = (float)s;
    const float nlf = (float)nl;
    const float den = fmaxf(nlf - 1.0f, 1.0f);
    const int   L   = NT + nl - NW;
    const float Lf  = (float)L;

    auto pos_of = [&](int j) -> float {
        float jf = (float)j;
        float pos;
        if (jf >= sf + nlf)      pos = jf - nlf + (float)NW;
        else if (jf >= sf)       pos = sf + (jf - sf) * (float)(NW - 1) / den;
        else                     pos = jf;
        return fminf(fmaxf(pos, 0.0f), (float)(NT - 1));
    };

    // ---- block-exact source window [winstart, winstart+span) ----
    int winstart, span;
    {
        float qp0 = (float)t0 * (Lf - 1.0f) / (float)(NT - 1);
        int   jlo = (int)floorf(qp0);
        float qpm = (float)(t0 + TPB - 1) * (Lf - 1.0f) / (float)(NT - 1);
        int   jhi = min((int)floorf(qpm) + 1, L - 1);
        float pmin = pos_of(jlo);
        float pmax = pos_of(jhi);
        winstart = ((int)floorf(pmin)) & ~3;
        if (winstart < 0) winstart = 0;
        int need_end = min((int)floorf(pmax) + 2, NT);
        span = (need_end - winstart + 3) & ~3;
        if (span > SPANROW) span = SPANROW;
        if (winstart + span > NT) winstart = NT - span;
    }

    // ---- stage: 16 rows x span floats, coalesced float4 ----
    const float* xb = x + (size_t)b * NC * NT;
    const int nv = span >> 2;
    #pragma unroll
    for (int it = 0; it < 8; ++it) {
        int idx  = it * TPB + tid;
        int c    = idx >> 7;
        int col4 = idx & 127;
        if (col4 < nv) {
            f32x4 v = *(const f32x4*)(xb + c * NT + winstart + col4 * 4);
            *(f32x4*)&lds[c][col4 * 4] = v;
        }
    }
    __syncthreads();

    // ---- per-thread: 4 strided t's (t0 + tq + 64*i), 4 channels ----
    const int tq = tid & 63;
    const int c0 = (tid >> 6) * 4;

    bool  two[4];
    float f0a[4], g0a[4], f1a[4], g1a[4], gqa[4], qfa[4];
    int   r0l[4], r0h[4], r1l[4], r1h[4];
    #pragma unroll
    for (int i = 0; i < 4; ++i) {
        const int t = t0 + tq + 64 * i;
        float qpos = (float)t * (Lf - 1.0f) / (float)(NT - 1);
        int   qlo  = (int)floorf(qpos);
        int   qhi  = min(qlo + 1, L - 1);
        qfa[i] = qpos - (float)qlo;
        gqa[i] = 1.0f - qfa[i];

        bool before = (qhi < s);
        bool after  = ((float)qlo >= sf + nlf);
        two[i] = before || after;
        if (two[i]) {
            // outside window: stage-1 position exact integer (f=0)
            const int off = after ? (NW - nl) : 0;
            r0l[i] = qlo + off - winstart;
            r1l[i] = qhi + off - winstart;
            r0h[i] = r0l[i]; r1h[i] = r1l[i];
            f0a[i] = 0.0f; g0a[i] = 1.0f;
            f1a[i] = 0.0f; g1a[i] = 1.0f;
        } else {
            float p0 = pos_of(qlo);
            int lo0 = (int)floorf(p0);
            int hi0 = min(lo0 + 1, NT - 1);
            f0a[i] = p0 - (float)lo0;
            g0a[i] = 1.0f - f0a[i];
            r0l[i] = lo0 - winstart;
            r0h[i] = hi0 - winstart;

            float p1 = pos_of(qhi);
            int lo1 = (int)floorf(p1);
            int hi1 = min(lo1 + 1, NT - 1);
            f1a[i] = p1 - (float)lo1;
            g1a[i] = 1.0f - f1a[i];
            r1l[i] = lo1 - winstart;
            r1h[i] = hi1 - winstart;
        }
    }

    float* ob = out + (size_t)b * NC * NT + t0 + tq;
    #pragma unroll
    for (int cc = 0; cc < 4; ++cc) {
        const int c = c0 + cc;
        #pragma unroll
        for (int i = 0; i < 4; ++i) {
            float r;
            if (two[i]) {
                // 2-tap exact path (halves LDS traffic)
                float a = lds[c][r0l[i]];
                float d = lds[c][r1l[i]];
                r = a * gqa[i] + d * qfa[i];
            } else {
                float a0 = lds[c][r0l[i]];
                float b0 = lds[c][r0h[i]];
                float a1 = lds[c][r1l[i]];
                float b1 = lds[c][r1h[i]];
                float v0 = a0 * g0a[i] + b0 * f0a[i];
                float v1 = a1 * g1a[i] + b1 * f1a[i];
                r = v0 * gqa[i] + v1 * qfa[i];
            }
            __builtin_nontemporal_store(r, ob + c * NT + 64 * i);
        }
    }
}

extern "C" void kernel_launch(void* const* d_in, const int* in_sizes, int n_in,
                              void* d_out, int out_size, void* d_ws, size_t ws_size,
                              hipStream_t stream) {
    const float* x   = (const float*)d_in[0];
    const int*   ws  = (const int*)d_in[1];
    const int*   nl  = (const int*)d_in[2];
    float*       out = (float*)d_out;

    dim3 grid(NT / TPB * NB);   // 8192 blocks, XCD-swizzled 1D
    dim3 block(TPB);
    rww_kernel<<<grid, block, 0, stream>>>(x, ws, nl, out);
}